// Round 8
// baseline (233.533 us; speedup 1.0000x reference)
//
#include <hip/hip_runtime.h>
#include <math.h>

static constexpr int NN    = 100000;
static constexpr int NBUCK = (NN + 255) / 256;   // 391 buckets of 256 nodes

#define CDIV(a,b) (((a)+(b)-1)/(b))

// bf16 helpers
__device__ __forceinline__ unsigned short f2bf(float f) {
    unsigned u = __float_as_uint(f);
    u += 0x7fffu + ((u >> 16) & 1u);
    return (unsigned short)(u >> 16);
}
__device__ __forceinline__ unsigned packbf(float lo, float hi) {
    return (unsigned)f2bf(lo) | ((unsigned)f2bf(hi) << 16);
}

// ------------------------------------------------------------------
__global__ __launch_bounds__(512) void k_zero(int* __restrict__ p, int n) {
    int i = blockIdx.x * 512 + threadIdx.x;
    if (i < n) p[i] = 0;
}

// A1: per-bucket edge counts (LDS hist, one global atomic per block-bucket)
__global__ __launch_bounds__(256) void k_bcount(const int* __restrict__ dst,
                                                int* __restrict__ bcnt,
                                                int E, int chunk) {
    __shared__ int lc[NBUCK];
    for (int i = threadIdx.x; i < NBUCK; i += 256) lc[i] = 0;
    __syncthreads();
    int e0 = blockIdx.x * chunk;
    int e1 = e0 + chunk; if (e1 > E) e1 = E;
    for (int e = e0 + threadIdx.x; e < e1; e += 256)
        atomicAdd(&lc[dst[e] >> 8], 1);
    __syncthreads();
    for (int i = threadIdx.x; i < NBUCK; i += 256)
        if (lc[i]) atomicAdd(&bcnt[i], lc[i]);
}

// exclusive scan of bucket counts -> bbase (and bfill copy)
__global__ __launch_bounds__(512) void k_bscan(const int* __restrict__ bcnt,
                                               int* __restrict__ bbase,
                                               int* __restrict__ bfill, int E) {
    __shared__ int sm[512];
    int t = threadIdx.x;
    int v = (t < NBUCK) ? bcnt[t] : 0;
    sm[t] = v; __syncthreads();
    for (int off = 1; off < 512; off <<= 1) {
        int u = (t >= off) ? sm[t - off] : 0;
        __syncthreads();
        sm[t] += u;
        __syncthreads();
    }
    if (t < NBUCK) { int ex = sm[t] - v; bbase[t] = ex; bfill[t] = ex; }
    if (t == 0) bbase[NBUCK] = E;
}

// A2: partition edges into bucket-contiguous part[], packed (src<<8)|(dst&255)
__global__ __launch_bounds__(256) void k_bpart(const int* __restrict__ src,
                                               const int* __restrict__ dst,
                                               int* __restrict__ bfill,
                                               unsigned int* __restrict__ part,
                                               int E, int chunk) {
    __shared__ int lc[NBUCK];
    __shared__ int boff[NBUCK];
    for (int i = threadIdx.x; i < NBUCK; i += 256) lc[i] = 0;
    __syncthreads();
    int e0 = blockIdx.x * chunk;
    int e1 = e0 + chunk; if (e1 > E) e1 = E;
    for (int e = e0 + threadIdx.x; e < e1; e += 256)
        atomicAdd(&lc[dst[e] >> 8], 1);
    __syncthreads();
    for (int i = threadIdx.x; i < NBUCK; i += 256) {
        int c = lc[i];
        boff[i] = c ? atomicAdd(&bfill[i], c) : 0;
        lc[i] = 0;
    }
    __syncthreads();
    for (int e = e0 + threadIdx.x; e < e1; e += 256) {
        int d = dst[e];
        int b = d >> 8;
        int pos = boff[b] + atomicAdd(&lc[b], 1);
        part[pos] = ((unsigned)src[e] << 8) | (unsigned)(d & 255);
    }
}

// B: per-bucket CSR finalize: row_ptr, dinv, col (all writes bucket-local)
__global__ __launch_bounds__(256) void k_bbuild(const unsigned int* __restrict__ part,
                                                const int* __restrict__ bbase,
                                                int* __restrict__ row_ptr,
                                                float* __restrict__ dinv,
                                                int* __restrict__ col, int n, int E) {
    __shared__ int hist[256];
    __shared__ int excl[256];
    __shared__ int fill[256];
    const int b = blockIdx.x;
    const int t = threadIdx.x;
    const int e0 = bbase[b], e1 = bbase[b + 1];
    hist[t] = 0; fill[t] = 0;
    __syncthreads();
    for (int e = e0 + t; e < e1; e += 256)
        atomicAdd(&hist[part[e] & 255], 1);
    __syncthreads();
    int v = hist[t];
    excl[t] = v; __syncthreads();
    for (int off = 1; off < 256; off <<= 1) {
        int u = (t >= off) ? excl[t - off] : 0;
        __syncthreads();
        excl[t] += u;
        __syncthreads();
    }
    int ex = excl[t] - v;
    int g = b * 256 + t;
    if (g < n) {
        row_ptr[g] = e0 + ex;
        dinv[g] = rsqrtf((float)(v + 1));
    }
    if (b == 0 && t == 0) row_ptr[n] = E;
    excl[t] = e0 + ex;
    __syncthreads();
    for (int e = e0 + t; e < e1; e += 256) {
        unsigned u = part[e];
        int ld = u & 255;
        int pos = excl[ld] + atomicAdd(&fill[ld], 1);
        col[pos] = (int)(u >> 8);
    }
}

// ------------------------------------------------------------------
// Layer-1 GEMM (K=512, NOUT=32): global_load_lds staging, double-buffered.
// LDS x row r holds quads rotated by (r>>1)&7 (conflict-free b128 reads);
// rotation applied via per-lane GLOBAL source offset, LDS dest stays linear.
__global__ __launch_bounds__(256) void k_gemm1(const float* __restrict__ X,
                                               const float* __restrict__ W,
                                               const float* __restrict__ dinv,
                                               unsigned short* __restrict__ OUT,
                                               int nrows) {
    constexpr int K    = 512;
    constexpr int NOUT = 32;
    constexpr int KC   = 32;
    constexpr int RPB  = 64;
    __shared__ float xs[2][RPB][KC];
    __shared__ float ws[2][KC][NOUT];

    const int t     = threadIdx.x;
    const int c0    = (t % 8) * 4;     // compute: 4 output cols
    const int slot  = t / 8;           // compute: row-pair slot (0..31)
    const int grow0 = blockIdx.x * RPB;
    const int srow  = t / 8;           // staging row (0..31)
    const int skq   = t % 8;           // staging k-quad
    const int wid8  = (t >> 6) * 8;    // wave's 8-row base (wave-uniform)

    float acc[2][4] = {{0.f,0.f,0.f,0.f},{0.f,0.f,0.f,0.f}};

    auto clampRow = [&](int lrow) {
        int rr = grow0 + lrow;
        return (rr > nrows - 1) ? (nrows - 1) : rr;
    };
    // pre-rotated global source column (quad rotation (srow>>1)&7)
    const int scol = ((skq - ((srow >> 1) & 7)) & 7) * 4;
    const float* xrowA = X + (size_t)clampRow(srow) * K + scol;
    const float* xrowB = X + (size_t)clampRow(32 + srow) * K + scol;

    auto stage = [&](int bf, int kc) {
        __builtin_amdgcn_global_load_lds(
            (const __attribute__((address_space(1))) void*)(xrowA + kc),
            (__attribute__((address_space(3))) void*)&xs[bf][wid8][0], 16, 0, 0);
        __builtin_amdgcn_global_load_lds(
            (const __attribute__((address_space(1))) void*)(xrowB + kc),
            (__attribute__((address_space(3))) void*)&xs[bf][32 + wid8][0], 16, 0, 0);
        __builtin_amdgcn_global_load_lds(
            (const __attribute__((address_space(1))) void*)(W + (size_t)(kc + srow) * NOUT + skq * 4),
            (__attribute__((address_space(3))) void*)&ws[bf][wid8][0], 16, 0, 0);
    };

    stage(0, 0);
    __syncthreads();

    int buf = 0;
    const int r0 = slot * 2;
    const int q4 = (slot & 7) * 4;     // read-side rotation (same for r0, r0+1)
    for (int kc = 0; kc < K; kc += KC) {
        const bool more = (kc + KC < K);
        if (more) stage(buf ^ 1, kc + KC);
        #pragma unroll
        for (int k = 0; k < KC; k += 4) {
            const int kq = (k + q4) & 31;
            float4 x0 = *(const float4*)&xs[buf][r0][kq];
            float4 x1 = *(const float4*)&xs[buf][r0 + 1][kq];
            float4 w0 = *(const float4*)&ws[buf][k + 0][c0];
            float4 w1 = *(const float4*)&ws[buf][k + 1][c0];
            float4 w2 = *(const float4*)&ws[buf][k + 2][c0];
            float4 w3 = *(const float4*)&ws[buf][k + 3][c0];
            acc[0][0] += x0.x*w0.x + x0.y*w1.x + x0.z*w2.x + x0.w*w3.x;
            acc[0][1] += x0.x*w0.y + x0.y*w1.y + x0.z*w2.y + x0.w*w3.y;
            acc[0][2] += x0.x*w0.z + x0.y*w1.z + x0.z*w2.z + x0.w*w3.z;
            acc[0][3] += x0.x*w0.w + x0.y*w1.w + x0.z*w2.w + x0.w*w3.w;
            acc[1][0] += x1.x*w0.x + x1.y*w1.x + x1.z*w2.x + x1.w*w3.x;
            acc[1][1] += x1.x*w0.y + x1.y*w1.y + x1.z*w2.y + x1.w*w3.y;
            acc[1][2] += x1.x*w0.z + x1.y*w1.z + x1.z*w2.z + x1.w*w3.z;
            acc[1][3] += x1.x*w0.w + x1.y*w1.w + x1.z*w2.w + x1.w*w3.w;
        }
        __syncthreads();               // drains global_load_lds + readers
        if (more) buf ^= 1;
    }
    #pragma unroll
    for (int r = 0; r < 2; r++) {
        int rr = grow0 + r0 + r;
        if (rr < nrows) {
            float d = dinv[rr];
            ushort4 o;
            o.x = f2bf(acc[r][0] * d); o.y = f2bf(acc[r][1] * d);
            o.z = f2bf(acc[r][2] * d); o.w = f2bf(acc[r][3] * d);
            *(ushort4*)&OUT[(size_t)rr * NOUT + c0] = o;
        }
    }
}

// ------------------------------------------------------------------
// bf16 gather core: 4 lanes/node, lane owns 8 channels, uint4 (16B) per edge.
__device__ __forceinline__ void acc8(float* a, uint4 u) {
    a[0] += __uint_as_float(u.x << 16);
    a[1] += __uint_as_float(u.x & 0xffff0000u);
    a[2] += __uint_as_float(u.y << 16);
    a[3] += __uint_as_float(u.y & 0xffff0000u);
    a[4] += __uint_as_float(u.z << 16);
    a[5] += __uint_as_float(u.z & 0xffff0000u);
    a[6] += __uint_as_float(u.w << 16);
    a[7] += __uint_as_float(u.w & 0xffff0000u);
}

// returns per-lane 8-channel aggregate (edges + self) into a[8]
__device__ __forceinline__ void agg_gather8(const unsigned short* __restrict__ HS,
                                            const int* __restrict__ col,
                                            int s0, int s1, int node, int c0h,
                                            float* __restrict__ out) {
    float a0[8], a1[8], a2[8], a3[8];
    #pragma unroll
    for (int j = 0; j < 8; j++) { a0[j] = a1[j] = a2[j] = a3[j] = 0.f; }
    const char* base = (const char*)HS + (size_t)c0h * 2;
    int e = s0;
    for (; e + 3 < s1; e += 4) {
        int sA = col[e], sB = col[e + 1], sC = col[e + 2], sD = col[e + 3];
        uint4 uA = *(const uint4*)(base + (size_t)sA * 64);
        uint4 uB = *(const uint4*)(base + (size_t)sB * 64);
        uint4 uC = *(const uint4*)(base + (size_t)sC * 64);
        uint4 uD = *(const uint4*)(base + (size_t)sD * 64);
        acc8(a0, uA); acc8(a1, uB); acc8(a2, uC); acc8(a3, uD);
    }
    for (; e < s1; e++) {
        uint4 uA = *(const uint4*)(base + (size_t)col[e] * 64);
        acc8(a0, uA);
    }
    uint4 uS = *(const uint4*)(base + (size_t)node * 64);
    acc8(a1, uS);
    #pragma unroll
    for (int j = 0; j < 8; j++) out[j] = (a0[j] + a1[j]) + (a2[j] + a3[j]);
}

// fuse: a = relu(dinv*(agg hs1) + b1); OUT(bf16) = dinv * (a @ W2)  [32->32]
__global__ __launch_bounds__(256) void k_fuse32(const unsigned short* __restrict__ HS,
                                                const int* __restrict__ row_ptr,
                                                const int* __restrict__ col,
                                                const float* __restrict__ dinv,
                                                const float* __restrict__ bin,
                                                const float* __restrict__ W,
                                                unsigned short* __restrict__ OUT, int n) {
    __shared__ float ws[32][32];
    {
        int i = threadIdx.x;                 // 256 float4s = 32x32
        int r = i / 8, c = (i % 8) * 4;
        *(float4*)&ws[r][c] = *(const float4*)&W[r * 32 + c];
    }
    __syncthreads();
    const int t    = threadIdx.x;
    const int node = blockIdx.x * 64 + t / 4;
    const int c0h  = (t % 4) * 8;            // 8 channels per lane
    if (node >= n) return;
    const int s0 = row_ptr[node], s1 = row_ptr[node + 1];
    float acc[8];
    agg_gather8(HS, col, s0, s1, node, c0h, acc);
    const float di = dinv[node];
    float a[8];
    #pragma unroll
    for (int j = 0; j < 8; j++)
        a[j] = fmaxf(di * acc[j] + bin[c0h + j], 0.f);
    float o[8] = {0,0,0,0,0,0,0,0};
    const int gb = (t & 63) & ~3;
    #pragma unroll
    for (int s = 0; s < 4; s++) {
        #pragma unroll
        for (int j = 0; j < 8; j++) {
            float av = __shfl(a[j], gb + s, 64);
            const int kr = s * 8 + j;
            float4 w0 = *(const float4*)&ws[kr][c0h];
            float4 w1 = *(const float4*)&ws[kr][c0h + 4];
            o[0] += av * w0.x; o[1] += av * w0.y; o[2] += av * w0.z; o[3] += av * w0.w;
            o[4] += av * w1.x; o[5] += av * w1.y; o[6] += av * w1.z; o[7] += av * w1.w;
        }
    }
    uint4 st;
    st.x = packbf(o[0] * di, o[1] * di);
    st.y = packbf(o[2] * di, o[3] * di);
    st.z = packbf(o[4] * di, o[5] * di);
    st.w = packbf(o[6] * di, o[7] * di);
    *(uint4*)&OUT[(size_t)node * 32 + c0h] = st;
}

// agg + bias + relu + dinv scale: OUT(bf16) = dinv.*relu(dinv*agg(HS)+b)
__global__ __launch_bounds__(256) void k_aggscale(const unsigned short* __restrict__ HS,
                                                  const int* __restrict__ row_ptr,
                                                  const int* __restrict__ col,
                                                  const float* __restrict__ dinv,
                                                  const float* __restrict__ bin,
                                                  unsigned short* __restrict__ OUT, int n) {
    const int t    = threadIdx.x;
    const int node = blockIdx.x * 64 + t / 4;
    const int c0h  = (t % 4) * 8;
    if (node >= n) return;
    const int s0 = row_ptr[node], s1 = row_ptr[node + 1];
    float acc[8];
    agg_gather8(HS, col, s0, s1, node, c0h, acc);
    const float di = dinv[node];
    float o[8];
    #pragma unroll
    for (int j = 0; j < 8; j++)
        o[j] = di * fmaxf(di * acc[j] + bin[c0h + j], 0.f);
    uint4 st;
    st.x = packbf(o[0], o[1]);
    st.y = packbf(o[2], o[3]);
    st.z = packbf(o[4], o[5]);
    st.w = packbf(o[6], o[7]);
    *(uint4*)&OUT[(size_t)node * 32 + c0h] = st;
}

// final: g = dinv*(agg ys2); h3 = g @ W3 + b3 [32->64]; out = log_softmax(h3)
__global__ __launch_bounds__(256) void k_fuseC(const unsigned short* __restrict__ YS,
                                               const int* __restrict__ row_ptr,
                                               const int* __restrict__ col,
                                               const float* __restrict__ dinv,
                                               const float* __restrict__ b3,
                                               const float* __restrict__ W,
                                               float* __restrict__ OUT, int n) {
    __shared__ float ws[32][64];
    {
        int i = threadIdx.x;                  // 512 float4s = 32x64 -> 2 each
        int r0w = i / 16, cw = (i % 16) * 4;
        *(float4*)&ws[r0w][cw]      = *(const float4*)&W[r0w * 64 + cw];
        *(float4*)&ws[r0w + 16][cw] = *(const float4*)&W[(r0w + 16) * 64 + cw];
    }
    __syncthreads();
    const int t    = threadIdx.x;
    const int node = blockIdx.x * 64 + t / 4;
    const int c0h  = (t % 4) * 8;             // gather channels
    const int c0f  = (t % 4) * 16;            // output channels (16 per lane)
    if (node >= n) return;
    const int s0 = row_ptr[node], s1 = row_ptr[node + 1];
    float acc[8];
    agg_gather8(YS, col, s0, s1, node, c0h, acc);
    const float di = dinv[node];
    float g[8];
    #pragma unroll
    for (int j = 0; j < 8; j++) g[j] = di * acc[j];
    float o[16];
    #pragma unroll
    for (int j = 0; j < 16; j++) o[j] = b3[c0f + j];
    const int gb = (t & 63) & ~3;
    #pragma unroll
    for (int s = 0; s < 4; s++) {
        #pragma unroll
        for (int j = 0; j < 8; j++) {
            float gv = __shfl(g[j], gb + s, 64);
            const int kr = s * 8 + j;
            float4 w0 = *(const float4*)&ws[kr][c0f];
            float4 w1 = *(const float4*)&ws[kr][c0f + 4];
            float4 w2 = *(const float4*)&ws[kr][c0f + 8];
            float4 w3 = *(const float4*)&ws[kr][c0f + 12];
            o[0]  += gv * w0.x; o[1]  += gv * w0.y; o[2]  += gv * w0.z; o[3]  += gv * w0.w;
            o[4]  += gv * w1.x; o[5]  += gv * w1.y; o[6]  += gv * w1.z; o[7]  += gv * w1.w;
            o[8]  += gv * w2.x; o[9]  += gv * w2.y; o[10] += gv * w2.z; o[11] += gv * w2.w;
            o[12] += gv * w3.x; o[13] += gv * w3.y; o[14] += gv * w3.z; o[15] += gv * w3.w;
        }
    }
    float m = o[0];
    #pragma unroll
    for (int j = 1; j < 16; j++) m = fmaxf(m, o[j]);
    #pragma unroll
    for (int off = 1; off < 4; off <<= 1) m = fmaxf(m, __shfl_xor(m, off, 64));
    float sum = 0.f;
    #pragma unroll
    for (int j = 0; j < 16; j++) sum += expf(o[j] - m);
    #pragma unroll
    for (int off = 1; off < 4; off <<= 1) sum += __shfl_xor(sum, off, 64);
    float lse = m + logf(sum);
    float4 r0v, r1v, r2v, r3v;
    r0v.x = o[0] - lse;  r0v.y = o[1] - lse;  r0v.z = o[2] - lse;  r0v.w = o[3] - lse;
    r1v.x = o[4] - lse;  r1v.y = o[5] - lse;  r1v.z = o[6] - lse;  r1v.w = o[7] - lse;
    r2v.x = o[8] - lse;  r2v.y = o[9] - lse;  r2v.z = o[10] - lse; r2v.w = o[11] - lse;
    r3v.x = o[12] - lse; r3v.y = o[13] - lse; r3v.z = o[14] - lse; r3v.w = o[15] - lse;
    float* ob = &OUT[(size_t)node * 64 + c0f];
    *(float4*)&ob[0]  = r0v;
    *(float4*)&ob[4]  = r1v;
    *(float4*)&ob[8]  = r2v;
    *(float4*)&ob[12] = r3v;
}

// ------------------------------------------------------------------
extern "C" void kernel_launch(void* const* d_in, const int* in_sizes, int n_in,
                              void* d_out, int out_size, void* d_ws, size_t ws_size,
                              hipStream_t stream) {
    const float* x  = (const float*)d_in[0];
    const int*   ei = (const int*)d_in[1];
    const float* W1 = (const float*)d_in[2];
    const float* b1 = (const float*)d_in[3];
    const float* W2 = (const float*)d_in[4];
    const float* b2 = (const float*)d_in[5];
    const float* W3 = (const float*)d_in[6];
    const float* b3 = (const float*)d_in[7];
    float* out = (float*)d_out;

    const int E = in_sizes[1] / 2;
    const int n = NN;
    const int* src = ei;
    const int* dst = ei + E;

    char* p = (char*)d_ws;
    auto alloc = [&](size_t bytes) -> void* {
        void* r = p;
        p += (bytes + 63) & ~(size_t)63;
        return r;
    };
    int*            bcnt    = (int*)alloc((size_t)NBUCK * 4);
    int*            bbase   = (int*)alloc((size_t)(NBUCK + 1) * 4);
    int*            bfill   = (int*)alloc((size_t)NBUCK * 4);
    unsigned*       part    = (unsigned*)alloc((size_t)E * 4);
    int*            row_ptr = (int*)alloc((size_t)(n + 1) * 4);
    int*            col     = (int*)alloc((size_t)E * 4);
    float*          dinv    = (float*)alloc((size_t)n * 4);
    unsigned short* hs1     = (unsigned short*)alloc((size_t)n * 32 * 2);  // reused as ys2
    unsigned short* hs2     = (unsigned short*)alloc((size_t)n * 32 * 2);

    const int NBLK_A = 256;
    const int chunk  = CDIV(E, NBLK_A);

    k_zero<<<1, 512, 0, stream>>>(bcnt, NBUCK);
    k_bcount<<<NBLK_A, 256, 0, stream>>>(dst, bcnt, E, chunk);
    k_bscan<<<1, 512, 0, stream>>>(bcnt, bbase, bfill, E);
    k_bpart<<<NBLK_A, 256, 0, stream>>>(src, dst, bfill, part, E, chunk);
    k_bbuild<<<NBUCK, 256, 0, stream>>>(part, bbase, row_ptr, dinv, col, n, E);

    // L1 GEMM: hs1 = bf16(dinv.*(x @ W1))
    k_gemm1<<<CDIV(n, 64), 256, 0, stream>>>(x, W1, dinv, hs1, n);
    // L1 agg + relu + L2 GEMM: hs2 = bf16(dinv.*(relu(dinv*agg(hs1)+b1) @ W2))
    k_fuse32<<<CDIV(n, 64), 256, 0, stream>>>(hs1, row_ptr, col, dinv, b1, W2, hs2, n);
    // L2 agg + relu + scale: ys2 = bf16(dinv.*relu(dinv*agg(hs2)+b2))  (reuse hs1)
    k_aggscale<<<CDIV(n, 64), 256, 0, stream>>>(hs2, row_ptr, col, dinv, b2, hs1, n);
    // L3 (commuted): out = lsm( (dinv*agg(ys2)) @ W3 + b3 )
    k_fuseC<<<CDIV(n, 64), 256, 0, stream>>>(hs1, row_ptr, col, dinv, b3, W3, out, n);
}

// Round 9
// 227.261 us; speedup vs baseline: 1.0276x; 1.0276x over previous
//
#include <hip/hip_runtime.h>
#include <math.h>

static constexpr int NN    = 100000;
static constexpr int NBUCK = (NN + 255) / 256;   // 391 buckets of 256 nodes

#define CDIV(a,b) (((a)+(b)-1)/(b))

// bf16 helpers (round-to-nearest-even store, shift load)
__device__ __forceinline__ float bf2f(unsigned short u) {
    return __uint_as_float(((unsigned)u) << 16);
}
__device__ __forceinline__ unsigned short f2bf(float f) {
    unsigned u = __float_as_uint(f);
    u += 0x7fffu + ((u >> 16) & 1u);
    return (unsigned short)(u >> 16);
}

// ------------------------------------------------------------------
__global__ __launch_bounds__(512) void k_zero(int* __restrict__ p, int n) {
    int i = blockIdx.x * 512 + threadIdx.x;
    if (i < n) p[i] = 0;
}

// A1: per-bucket edge counts (LDS hist, one global atomic per block-bucket)
__global__ __launch_bounds__(256) void k_bcount(const int* __restrict__ dst,
                                                int* __restrict__ bcnt,
                                                int E, int chunk) {
    __shared__ int lc[NBUCK];
    for (int i = threadIdx.x; i < NBUCK; i += 256) lc[i] = 0;
    __syncthreads();
    int e0 = blockIdx.x * chunk;
    int e1 = e0 + chunk; if (e1 > E) e1 = E;
    for (int e = e0 + threadIdx.x; e < e1; e += 256)
        atomicAdd(&lc[dst[e] >> 8], 1);
    __syncthreads();
    for (int i = threadIdx.x; i < NBUCK; i += 256)
        if (lc[i]) atomicAdd(&bcnt[i], lc[i]);
}

// exclusive scan of bucket counts -> bbase (and bfill copy)
__global__ __launch_bounds__(512) void k_bscan(const int* __restrict__ bcnt,
                                               int* __restrict__ bbase,
                                               int* __restrict__ bfill, int E) {
    __shared__ int sm[512];
    int t = threadIdx.x;
    int v = (t < NBUCK) ? bcnt[t] : 0;
    sm[t] = v; __syncthreads();
    for (int off = 1; off < 512; off <<= 1) {
        int u = (t >= off) ? sm[t - off] : 0;
        __syncthreads();
        sm[t] += u;
        __syncthreads();
    }
    if (t < NBUCK) { int ex = sm[t] - v; bbase[t] = ex; bfill[t] = ex; }
    if (t == 0) bbase[NBUCK] = E;
}

// A2: partition edges into bucket-contiguous part[], packed (src<<8)|(dst&255)
__global__ __launch_bounds__(256) void k_bpart(const int* __restrict__ src,
                                               const int* __restrict__ dst,
                                               int* __restrict__ bfill,
                                               unsigned int* __restrict__ part,
                                               int E, int chunk) {
    __shared__ int lc[NBUCK];
    __shared__ int boff[NBUCK];
    for (int i = threadIdx.x; i < NBUCK; i += 256) lc[i] = 0;
    __syncthreads();
    int e0 = blockIdx.x * chunk;
    int e1 = e0 + chunk; if (e1 > E) e1 = E;
    for (int e = e0 + threadIdx.x; e < e1; e += 256)
        atomicAdd(&lc[dst[e] >> 8], 1);
    __syncthreads();
    for (int i = threadIdx.x; i < NBUCK; i += 256) {
        int c = lc[i];
        boff[i] = c ? atomicAdd(&bfill[i], c) : 0;
        lc[i] = 0;
    }
    __syncthreads();
    for (int e = e0 + threadIdx.x; e < e1; e += 256) {
        int d = dst[e];
        int b = d >> 8;
        int pos = boff[b] + atomicAdd(&lc[b], 1);
        part[pos] = ((unsigned)src[e] << 8) | (unsigned)(d & 255);
    }
}

// B: per-bucket CSR finalize: row_ptr, dinv, col (all writes bucket-local)
__global__ __launch_bounds__(256) void k_bbuild(const unsigned int* __restrict__ part,
                                                const int* __restrict__ bbase,
                                                int* __restrict__ row_ptr,
                                                float* __restrict__ dinv,
                                                int* __restrict__ col, int n, int E) {
    __shared__ int hist[256];
    __shared__ int excl[256];
    __shared__ int fill[256];
    const int b = blockIdx.x;
    const int t = threadIdx.x;
    const int e0 = bbase[b], e1 = bbase[b + 1];
    hist[t] = 0; fill[t] = 0;
    __syncthreads();
    for (int e = e0 + t; e < e1; e += 256)
        atomicAdd(&hist[part[e] & 255], 1);
    __syncthreads();
    int v = hist[t];
    excl[t] = v; __syncthreads();
    for (int off = 1; off < 256; off <<= 1) {
        int u = (t >= off) ? excl[t - off] : 0;
        __syncthreads();
        excl[t] += u;
        __syncthreads();
    }
    int ex = excl[t] - v;
    int g = b * 256 + t;
    if (g < n) {
        row_ptr[g] = e0 + ex;
        dinv[g] = rsqrtf((float)(v + 1));
    }
    if (b == 0 && t == 0) row_ptr[n] = E;
    excl[t] = e0 + ex;
    __syncthreads();
    for (int e = e0 + t; e < e1; e += 256) {
        unsigned u = part[e];
        int ld = u & 255;
        int pos = excl[ld] + atomicAdd(&fill[ld], 1);
        col[pos] = (int)(u >> 8);
    }
}

// ------------------------------------------------------------------
// Layer-1 GEMM (K=512, NOUT=32): global_load_lds staging, double-buffered.
// LDS x row r holds quads rotated by (r>>1)&7 (conflict-free b128 reads);
// rotation applied via per-lane GLOBAL source offset, LDS dest stays linear.
__global__ __launch_bounds__(256) void k_gemm1(const float* __restrict__ X,
                                               const float* __restrict__ W,
                                               const float* __restrict__ dinv,
                                               unsigned short* __restrict__ OUT,
                                               int nrows) {
    constexpr int K    = 512;
    constexpr int NOUT = 32;
    constexpr int KC   = 32;
    constexpr int RPB  = 64;
    __shared__ float xs[2][RPB][KC];
    __shared__ float ws[2][KC][NOUT];

    const int t     = threadIdx.x;
    const int c0    = (t % 8) * 4;     // compute: 4 output cols
    const int slot  = t / 8;           // compute: row-pair slot (0..31)
    const int grow0 = blockIdx.x * RPB;
    const int srow  = t / 8;           // staging row (0..31)
    const int skq   = t % 8;           // staging k-quad
    const int wid8  = (t >> 6) * 8;    // wave's 8-row base (wave-uniform)

    float acc[2][4] = {{0.f,0.f,0.f,0.f},{0.f,0.f,0.f,0.f}};

    auto clampRow = [&](int lrow) {
        int rr = grow0 + lrow;
        return (rr > nrows - 1) ? (nrows - 1) : rr;
    };
    // pre-rotated global source column (quad rotation (srow>>1)&7)
    const int scol = ((skq - ((srow >> 1) & 7)) & 7) * 4;
    const float* xrowA = X + (size_t)clampRow(srow) * K + scol;
    const float* xrowB = X + (size_t)clampRow(32 + srow) * K + scol;

    auto stage = [&](int bf, int kc) {
        __builtin_amdgcn_global_load_lds(
            (const __attribute__((address_space(1))) void*)(xrowA + kc),
            (__attribute__((address_space(3))) void*)&xs[bf][wid8][0], 16, 0, 0);
        __builtin_amdgcn_global_load_lds(
            (const __attribute__((address_space(1))) void*)(xrowB + kc),
            (__attribute__((address_space(3))) void*)&xs[bf][32 + wid8][0], 16, 0, 0);
        __builtin_amdgcn_global_load_lds(
            (const __attribute__((address_space(1))) void*)(W + (size_t)(kc + srow) * NOUT + skq * 4),
            (__attribute__((address_space(3))) void*)&ws[bf][wid8][0], 16, 0, 0);
    };

    stage(0, 0);
    __syncthreads();

    int buf = 0;
    const int r0 = slot * 2;
    const int q4 = (slot & 7) * 4;     // read-side rotation (same for r0, r0+1)
    for (int kc = 0; kc < K; kc += KC) {
        const bool more = (kc + KC < K);
        if (more) stage(buf ^ 1, kc + KC);
        #pragma unroll
        for (int k = 0; k < KC; k += 4) {
            const int kq = (k + q4) & 31;
            float4 x0 = *(const float4*)&xs[buf][r0][kq];
            float4 x1 = *(const float4*)&xs[buf][r0 + 1][kq];
            float4 w0 = *(const float4*)&ws[buf][k + 0][c0];
            float4 w1 = *(const float4*)&ws[buf][k + 1][c0];
            float4 w2 = *(const float4*)&ws[buf][k + 2][c0];
            float4 w3 = *(const float4*)&ws[buf][k + 3][c0];
            acc[0][0] += x0.x*w0.x + x0.y*w1.x + x0.z*w2.x + x0.w*w3.x;
            acc[0][1] += x0.x*w0.y + x0.y*w1.y + x0.z*w2.y + x0.w*w3.y;
            acc[0][2] += x0.x*w0.z + x0.y*w1.z + x0.z*w2.z + x0.w*w3.z;
            acc[0][3] += x0.x*w0.w + x0.y*w1.w + x0.z*w2.w + x0.w*w3.w;
            acc[1][0] += x1.x*w0.x + x1.y*w1.x + x1.z*w2.x + x1.w*w3.x;
            acc[1][1] += x1.x*w0.y + x1.y*w1.y + x1.z*w2.y + x1.w*w3.y;
            acc[1][2] += x1.x*w0.z + x1.y*w1.z + x1.z*w2.z + x1.w*w3.z;
            acc[1][3] += x1.x*w0.w + x1.y*w1.w + x1.z*w2.w + x1.w*w3.w;
        }
        __syncthreads();               // drains global_load_lds + readers
        if (more) buf ^= 1;
    }
    #pragma unroll
    for (int r = 0; r < 2; r++) {
        int rr = grow0 + r0 + r;
        if (rr < nrows) {
            float d = dinv[rr];
            ushort4 o;
            o.x = f2bf(acc[r][0] * d); o.y = f2bf(acc[r][1] * d);
            o.z = f2bf(acc[r][2] * d); o.w = f2bf(acc[r][3] * d);
            *(ushort4*)&OUT[(size_t)rr * NOUT + c0] = o;
        }
    }
}

// ------------------------------------------------------------------
// bf16 gather-aggregate core: 8 lanes/node, lane owns channels [c0..c0+3].
// 4 independent chains -> 32 outstanding 8B requests per node (MLP-bound).
__device__ __forceinline__ float4 agg_gather_bf16(const unsigned short* __restrict__ HS,
                                                  const int* __restrict__ col,
                                                  int s0, int s1, int node, int c0) {
    float4 a0 = {0,0,0,0}, a1 = {0,0,0,0}, a2 = {0,0,0,0}, a3 = {0,0,0,0};
    int e = s0;
    for (; e + 3 < s1; e += 4) {
        int sA = col[e], sB = col[e + 1], sC = col[e + 2], sD = col[e + 3];
        ushort4 uA = *(const ushort4*)&HS[(size_t)sA * 32 + c0];
        ushort4 uB = *(const ushort4*)&HS[(size_t)sB * 32 + c0];
        ushort4 uC = *(const ushort4*)&HS[(size_t)sC * 32 + c0];
        ushort4 uD = *(const ushort4*)&HS[(size_t)sD * 32 + c0];
        a0.x += bf2f(uA.x); a0.y += bf2f(uA.y); a0.z += bf2f(uA.z); a0.w += bf2f(uA.w);
        a1.x += bf2f(uB.x); a1.y += bf2f(uB.y); a1.z += bf2f(uB.z); a1.w += bf2f(uB.w);
        a2.x += bf2f(uC.x); a2.y += bf2f(uC.y); a2.z += bf2f(uC.z); a2.w += bf2f(uC.w);
        a3.x += bf2f(uD.x); a3.y += bf2f(uD.y); a3.z += bf2f(uD.z); a3.w += bf2f(uD.w);
    }
    for (; e < s1; e++) {
        int sA = col[e];
        ushort4 uA = *(const ushort4*)&HS[(size_t)sA * 32 + c0];
        a0.x += bf2f(uA.x); a0.y += bf2f(uA.y); a0.z += bf2f(uA.z); a0.w += bf2f(uA.w);
    }
    ushort4 uS = *(const ushort4*)&HS[(size_t)node * 32 + c0];
    float4 acc;
    acc.x = a0.x + a1.x + a2.x + a3.x + bf2f(uS.x);
    acc.y = a0.y + a1.y + a2.y + a3.y + bf2f(uS.y);
    acc.z = a0.z + a1.z + a2.z + a3.z + bf2f(uS.z);
    acc.w = a0.w + a1.w + a2.w + a3.w + bf2f(uS.w);
    return acc;
}

// fuse: a = relu(dinv*(agg hs1) + b1); OUT(bf16) = dinv * (a @ W2)  [32 -> 32]
__global__ __launch_bounds__(256) void k_fuse32(const unsigned short* __restrict__ HS,
                                                const int* __restrict__ row_ptr,
                                                const int* __restrict__ col,
                                                const float* __restrict__ dinv,
                                                const float* __restrict__ bin,
                                                const float* __restrict__ W,
                                                unsigned short* __restrict__ OUT, int n) {
    __shared__ float ws[32][32];
    {
        int i = threadIdx.x;                 // 256 float4s = 32x32
        int r = i / 8, c = (i % 8) * 4;
        *(float4*)&ws[r][c] = *(const float4*)&W[r * 32 + c];
    }
    __syncthreads();
    const int t    = threadIdx.x;
    const int node = blockIdx.x * 32 + t / 8;
    const int c0   = (t % 8) * 4;
    if (node >= n) return;
    const int s0 = row_ptr[node], s1 = row_ptr[node + 1];
    float4 acc = agg_gather_bf16(HS, col, s0, s1, node, c0);
    const float di = dinv[node];
    float4 b4 = *(const float4*)&bin[c0];
    float4 a;
    a.x = fmaxf(di * acc.x + b4.x, 0.f);
    a.y = fmaxf(di * acc.y + b4.y, 0.f);
    a.z = fmaxf(di * acc.z + b4.z, 0.f);
    a.w = fmaxf(di * acc.w + b4.w, 0.f);
    float4 o = {0,0,0,0};
    const int gb = (t & 63) & ~7;
    #pragma unroll
    for (int s = 0; s < 8; s++) {
        float4 as;
        as.x = __shfl(a.x, gb + s, 64);
        as.y = __shfl(a.y, gb + s, 64);
        as.z = __shfl(a.z, gb + s, 64);
        as.w = __shfl(a.w, gb + s, 64);
        const int k0 = s * 4;
        float4 w0 = *(const float4*)&ws[k0 + 0][c0];
        float4 w1 = *(const float4*)&ws[k0 + 1][c0];
        float4 w2 = *(const float4*)&ws[k0 + 2][c0];
        float4 w3 = *(const float4*)&ws[k0 + 3][c0];
        o.x += as.x*w0.x + as.y*w1.x + as.z*w2.x + as.w*w3.x;
        o.y += as.x*w0.y + as.y*w1.y + as.z*w2.y + as.w*w3.y;
        o.z += as.x*w0.z + as.y*w1.z + as.z*w2.z + as.w*w3.z;
        o.w += as.x*w0.w + as.y*w1.w + as.z*w2.w + as.w*w3.w;
    }
    ushort4 st;
    st.x = f2bf(o.x * di); st.y = f2bf(o.y * di);
    st.z = f2bf(o.z * di); st.w = f2bf(o.w * di);
    *(ushort4*)&OUT[(size_t)node * 32 + c0] = st;
}

// agg + bias + relu + dinv scale: OUT(bf16) = dinv.*relu(dinv*agg(HS)+b)
__global__ __launch_bounds__(256) void k_aggscale(const unsigned short* __restrict__ HS,
                                                  const int* __restrict__ row_ptr,
                                                  const int* __restrict__ col,
                                                  const float* __restrict__ dinv,
                                                  const float* __restrict__ bin,
                                                  unsigned short* __restrict__ OUT, int n) {
    const int t    = threadIdx.x;
    const int node = blockIdx.x * 32 + t / 8;
    const int c0   = (t % 8) * 4;
    if (node >= n) return;
    const int s0 = row_ptr[node], s1 = row_ptr[node + 1];
    float4 acc = agg_gather_bf16(HS, col, s0, s1, node, c0);
    const float di = dinv[node];
    float4 b4 = *(const float4*)&bin[c0];
    ushort4 o;
    o.x = f2bf(di * fmaxf(di * acc.x + b4.x, 0.f));
    o.y = f2bf(di * fmaxf(di * acc.y + b4.y, 0.f));
    o.z = f2bf(di * fmaxf(di * acc.z + b4.z, 0.f));
    o.w = f2bf(di * fmaxf(di * acc.w + b4.w, 0.f));
    *(ushort4*)&OUT[(size_t)node * 32 + c0] = o;
}

// final: g = dinv*(agg ys2); h3 = g @ W3 + b3 [32->64]; out = log_softmax(h3)
__global__ __launch_bounds__(256) void k_fuseC(const unsigned short* __restrict__ YS,
                                               const int* __restrict__ row_ptr,
                                               const int* __restrict__ col,
                                               const float* __restrict__ dinv,
                                               const float* __restrict__ b3,
                                               const float* __restrict__ W,
                                               float* __restrict__ OUT, int n) {
    __shared__ float ws[32][64];
    {
        int i = threadIdx.x;                  // 512 float4s = 32x64 -> 2 each
        int r0w = i / 16, cw = (i % 16) * 4;
        *(float4*)&ws[r0w][cw]      = *(const float4*)&W[r0w * 64 + cw];
        *(float4*)&ws[r0w + 16][cw] = *(const float4*)&W[(r0w + 16) * 64 + cw];
    }
    __syncthreads();
    const int t    = threadIdx.x;
    const int node = blockIdx.x * 32 + t / 8;
    const int c0   = (t % 8) * 4;
    if (node >= n) return;
    const int s0 = row_ptr[node], s1 = row_ptr[node + 1];
    float4 acc = agg_gather_bf16(YS, col, s0, s1, node, c0);
    const float di = dinv[node];
    float4 g;
    g.x = di * acc.x; g.y = di * acc.y; g.z = di * acc.z; g.w = di * acc.w;
    float4 oL = {0,0,0,0}, oH = {0,0,0,0};
    const int gb = (t & 63) & ~7;
    #pragma unroll
    for (int s = 0; s < 8; s++) {
        float4 gs;
        gs.x = __shfl(g.x, gb + s, 64);
        gs.y = __shfl(g.y, gb + s, 64);
        gs.z = __shfl(g.z, gb + s, 64);
        gs.w = __shfl(g.w, gb + s, 64);
        const int k0 = s * 4;
        #pragma unroll
        for (int q = 0; q < 4; q++) {
            float gv = (q == 0) ? gs.x : (q == 1) ? gs.y : (q == 2) ? gs.z : gs.w;
            float4 wL = *(const float4*)&ws[k0 + q][c0];
            float4 wH = *(const float4*)&ws[k0 + q][32 + c0];
            oL.x += gv * wL.x; oL.y += gv * wL.y; oL.z += gv * wL.z; oL.w += gv * wL.w;
            oH.x += gv * wH.x; oH.y += gv * wH.y; oH.z += gv * wH.z; oH.w += gv * wH.w;
        }
    }
    float4 bL = *(const float4*)&b3[c0];
    float4 bH = *(const float4*)&b3[32 + c0];
    oL.x += bL.x; oL.y += bL.y; oL.z += bL.z; oL.w += bL.w;
    oH.x += bH.x; oH.y += bH.y; oH.z += bH.z; oH.w += bH.w;
    float m = fmaxf(fmaxf(fmaxf(oL.x, oL.y), fmaxf(oL.z, oL.w)),
                    fmaxf(fmaxf(oH.x, oH.y), fmaxf(oH.z, oH.w)));
    #pragma unroll
    for (int off = 1; off < 8; off <<= 1) m = fmaxf(m, __shfl_xor(m, off, 64));
    float sum = expf(oL.x - m) + expf(oL.y - m) + expf(oL.z - m) + expf(oL.w - m)
              + expf(oH.x - m) + expf(oH.y - m) + expf(oH.z - m) + expf(oH.w - m);
    #pragma unroll
    for (int off = 1; off < 8; off <<= 1) sum += __shfl_xor(sum, off, 64);
    float lse = m + logf(sum);
    float4 rL, rH;
    rL.x = oL.x - lse; rL.y = oL.y - lse; rL.z = oL.z - lse; rL.w = oL.w - lse;
    rH.x = oH.x - lse; rH.y = oH.y - lse; rH.z = oH.z - lse; rH.w = oH.w - lse;
    *(float4*)&OUT[(size_t)node * 64 + c0]      = rL;
    *(float4*)&OUT[(size_t)node * 64 + 32 + c0] = rH;
}

// ------------------------------------------------------------------
extern "C" void kernel_launch(void* const* d_in, const int* in_sizes, int n_in,
                              void* d_out, int out_size, void* d_ws, size_t ws_size,
                              hipStream_t stream) {
    const float* x  = (const float*)d_in[0];
    const int*   ei = (const int*)d_in[1];
    const float* W1 = (const float*)d_in[2];
    const float* b1 = (const float*)d_in[3];
    const float* W2 = (const float*)d_in[4];
    const float* b2 = (const float*)d_in[5];
    const float* W3 = (const float*)d_in[6];
    const float* b3 = (const float*)d_in[7];
    float* out = (float*)d_out;

    const int E = in_sizes[1] / 2;
    const int n = NN;
    const int* src = ei;
    const int* dst = ei + E;

    char* p = (char*)d_ws;
    auto alloc = [&](size_t bytes) -> void* {
        void* r = p;
        p += (bytes + 63) & ~(size_t)63;
        return r;
    };
    int*            bcnt    = (int*)alloc((size_t)NBUCK * 4);
    int*            bbase   = (int*)alloc((size_t)(NBUCK + 1) * 4);
    int*            bfill   = (int*)alloc((size_t)NBUCK * 4);
    unsigned*       part    = (unsigned*)alloc((size_t)E * 4);
    int*            row_ptr = (int*)alloc((size_t)(n + 1) * 4);
    int*            col     = (int*)alloc((size_t)E * 4);
    float*          dinv    = (float*)alloc((size_t)n * 4);
    unsigned short* hs1     = (unsigned short*)alloc((size_t)n * 32 * 2);  // reused as ys2
    unsigned short* hs2     = (unsigned short*)alloc((size_t)n * 32 * 2);

    const int NBLK_A = 256;
    const int chunk  = CDIV(E, NBLK_A);

    k_zero<<<1, 512, 0, stream>>>(bcnt, NBUCK);
    k_bcount<<<NBLK_A, 256, 0, stream>>>(dst, bcnt, E, chunk);
    k_bscan<<<1, 512, 0, stream>>>(bcnt, bbase, bfill, E);
    k_bpart<<<NBLK_A, 256, 0, stream>>>(src, dst, bfill, part, E, chunk);
    k_bbuild<<<NBUCK, 256, 0, stream>>>(part, bbase, row_ptr, dinv, col, n, E);

    // L1 GEMM: hs1 = bf16(dinv.*(x @ W1))
    k_gemm1<<<CDIV(n, 64), 256, 0, stream>>>(x, W1, dinv, hs1, n);
    // L1 agg + relu + L2 GEMM: hs2 = bf16(dinv.*(relu(dinv*agg(hs1)+b1) @ W2))
    k_fuse32<<<CDIV(n, 32), 256, 0, stream>>>(hs1, row_ptr, col, dinv, b1, W2, hs2, n);
    // L2 agg + relu + scale: ys2 = bf16(dinv.*relu(dinv*agg(hs2)+b2))  (reuse hs1)
    k_aggscale<<<CDIV(n, 32), 256, 0, stream>>>(hs2, row_ptr, col, dinv, b2, hs1, n);
    // L3 (commuted): out = lsm( (dinv*agg(ys2)) @ W3 + b3 )
    k_fuseC<<<CDIV(n, 32), 256, 0, stream>>>(hs1, row_ptr, col, dinv, b3, W3, out, n);
}

// Round 10
// 185.397 us; speedup vs baseline: 1.2596x; 1.2258x over previous
//
#include <hip/hip_runtime.h>
#include <math.h>

static constexpr int NN    = 100000;
static constexpr int NBUCK = (NN + 255) / 256;   // 391 buckets of 256 nodes

#define CDIV(a,b) (((a)+(b)-1)/(b))

typedef __attribute__((ext_vector_type(8))) short bf16x8;
typedef __attribute__((ext_vector_type(4))) float f32x4;

// bf16 helpers (round-to-nearest-even store, shift load)
__device__ __forceinline__ float bf2f(unsigned short u) {
    return __uint_as_float(((unsigned)u) << 16);
}
__device__ __forceinline__ unsigned short f2bf(float f) {
    unsigned u = __float_as_uint(f);
    u += 0x7fffu + ((u >> 16) & 1u);
    return (unsigned short)(u >> 16);
}

// ------------------------------------------------------------------
__global__ __launch_bounds__(512) void k_zero(int* __restrict__ p, int n) {
    int i = blockIdx.x * 512 + threadIdx.x;
    if (i < n) p[i] = 0;
}

// Convert W1 [512][32] f32 -> swizzled bf16 image WT[c][512]:
// WT[c*512 + ((k>>3)^(c&7))*8 + (k&7)] = bf16(W[k][c])
__global__ __launch_bounds__(256) void k_wconv(const float* __restrict__ W,
                                               unsigned short* __restrict__ WT) {
    int i = blockIdx.x * 256 + threadIdx.x;   // 16384
    int k = i >> 5, c = i & 31;
    WT[c * 512 + (((k >> 3) ^ (c & 7)) << 3) + (k & 7)] = f2bf(W[i]);
}

// A1: per-bucket edge counts (LDS hist, one global atomic per block-bucket)
__global__ __launch_bounds__(256) void k_bcount(const int* __restrict__ dst,
                                                int* __restrict__ bcnt,
                                                int E, int chunk) {
    __shared__ int lc[NBUCK];
    for (int i = threadIdx.x; i < NBUCK; i += 256) lc[i] = 0;
    __syncthreads();
    int e0 = blockIdx.x * chunk;
    int e1 = e0 + chunk; if (e1 > E) e1 = E;
    for (int e = e0 + threadIdx.x; e < e1; e += 256)
        atomicAdd(&lc[dst[e] >> 8], 1);
    __syncthreads();
    for (int i = threadIdx.x; i < NBUCK; i += 256)
        if (lc[i]) atomicAdd(&bcnt[i], lc[i]);
}

// exclusive scan of bucket counts -> bbase (and bfill copy)
__global__ __launch_bounds__(512) void k_bscan(const int* __restrict__ bcnt,
                                               int* __restrict__ bbase,
                                               int* __restrict__ bfill, int E) {
    __shared__ int sm[512];
    int t = threadIdx.x;
    int v = (t < NBUCK) ? bcnt[t] : 0;
    sm[t] = v; __syncthreads();
    for (int off = 1; off < 512; off <<= 1) {
        int u = (t >= off) ? sm[t - off] : 0;
        __syncthreads();
        sm[t] += u;
        __syncthreads();
    }
    if (t < NBUCK) { int ex = sm[t] - v; bbase[t] = ex; bfill[t] = ex; }
    if (t == 0) bbase[NBUCK] = E;
}

// A2: partition edges into bucket-contiguous part[], packed (src<<8)|(dst&255)
__global__ __launch_bounds__(256) void k_bpart(const int* __restrict__ src,
                                               const int* __restrict__ dst,
                                               int* __restrict__ bfill,
                                               unsigned int* __restrict__ part,
                                               int E, int chunk) {
    __shared__ int lc[NBUCK];
    __shared__ int boff[NBUCK];
    for (int i = threadIdx.x; i < NBUCK; i += 256) lc[i] = 0;
    __syncthreads();
    int e0 = blockIdx.x * chunk;
    int e1 = e0 + chunk; if (e1 > E) e1 = E;
    for (int e = e0 + threadIdx.x; e < e1; e += 256)
        atomicAdd(&lc[dst[e] >> 8], 1);
    __syncthreads();
    for (int i = threadIdx.x; i < NBUCK; i += 256) {
        int c = lc[i];
        boff[i] = c ? atomicAdd(&bfill[i], c) : 0;
        lc[i] = 0;
    }
    __syncthreads();
    for (int e = e0 + threadIdx.x; e < e1; e += 256) {
        int d = dst[e];
        int b = d >> 8;
        int pos = boff[b] + atomicAdd(&lc[b], 1);
        part[pos] = ((unsigned)src[e] << 8) | (unsigned)(d & 255);
    }
}

// B: per-bucket CSR finalize: row_ptr, dinv, col (all writes bucket-local)
__global__ __launch_bounds__(256) void k_bbuild(const unsigned int* __restrict__ part,
                                                const int* __restrict__ bbase,
                                                int* __restrict__ row_ptr,
                                                float* __restrict__ dinv,
                                                int* __restrict__ col, int n, int E) {
    __shared__ int hist[256];
    __shared__ int excl[256];
    __shared__ int fill[256];
    const int b = blockIdx.x;
    const int t = threadIdx.x;
    const int e0 = bbase[b], e1 = bbase[b + 1];
    hist[t] = 0; fill[t] = 0;
    __syncthreads();
    for (int e = e0 + t; e < e1; e += 256)
        atomicAdd(&hist[part[e] & 255], 1);
    __syncthreads();
    int v = hist[t];
    excl[t] = v; __syncthreads();
    for (int off = 1; off < 256; off <<= 1) {
        int u = (t >= off) ? excl[t - off] : 0;
        __syncthreads();
        excl[t] += u;
        __syncthreads();
    }
    int ex = excl[t] - v;
    int g = b * 256 + t;
    if (g < n) {
        row_ptr[g] = e0 + ex;
        dinv[g] = rsqrtf((float)(v + 1));
    }
    if (b == 0 && t == 0) row_ptr[n] = E;
    excl[t] = e0 + ex;
    __syncthreads();
    for (int e = e0 + t; e < e1; e += 256) {
        unsigned u = part[e];
        int ld = u & 255;
        int pos = excl[ld] + atomicAdd(&fill[ld], 1);
        col[pos] = (int)(u >> 8);
    }
}

// ------------------------------------------------------------------
// Layer-1 GEMM via MFMA bf16: OUT(bf16) = dinv .* (x @ W1).
// 4 waves/block, 16 rows/wave, W1 resident in LDS (swizzled image, loaded
// once, no barrier in K-loop). A-frags straight from global with in-reg
// f32->bf16 convert; B-frags ds_read_b128 (XOR swizzle -> 2-way, free).
__global__ __launch_bounds__(256) void k_gemm1(const float* __restrict__ X,
                                               const unsigned short* __restrict__ WT,
                                               const float* __restrict__ dinv,
                                               unsigned short* __restrict__ OUT,
                                               int nrows) {
    __shared__ unsigned short wt[32][512];   // 32 KB
    const int t = threadIdx.x;
    {
        const uint4* s = (const uint4*)WT;
        uint4* d = (uint4*)&wt[0][0];
        #pragma unroll
        for (int i = 0; i < 8; i++) d[t + 256 * i] = s[t + 256 * i];
    }
    __syncthreads();

    const int lane  = t & 63;
    const int w     = t >> 6;
    const int grow0 = blockIdx.x * 64 + w * 16;
    const int m     = lane & 15;
    const int kb    = lane >> 4;             // 0..3
    int row = grow0 + m; if (row > nrows - 1) row = nrows - 1;
    const float* xrow = X + (size_t)row * 512 + kb * 8;

    f32x4 acc0 = {0.f, 0.f, 0.f, 0.f};
    f32x4 acc1 = {0.f, 0.f, 0.f, 0.f};
    const int mx  = m & 7;
    const unsigned short* wrow0 = &wt[m][0];
    const unsigned short* wrow1 = &wt[m + 16][0];

    #pragma unroll 4
    for (int kk = 0; kk < 512; kk += 32) {
        float4 xa = *(const float4*)(xrow + kk);
        float4 xb = *(const float4*)(xrow + kk + 4);
        bf16x8 a;
        a[0] = (short)f2bf(xa.x); a[1] = (short)f2bf(xa.y);
        a[2] = (short)f2bf(xa.z); a[3] = (short)f2bf(xa.w);
        a[4] = (short)f2bf(xb.x); a[5] = (short)f2bf(xb.y);
        a[6] = (short)f2bf(xb.z); a[7] = (short)f2bf(xb.w);
        const int g = (kk >> 3) + kb;        // 0..63
        bf16x8 b0 = *(const bf16x8*)&wrow0[((g ^ mx) & 63) * 8];
        bf16x8 b1 = *(const bf16x8*)&wrow1[((g ^ mx) & 63) * 8];
        acc0 = __builtin_amdgcn_mfma_f32_16x16x32_bf16(a, b0, acc0, 0, 0, 0);
        acc1 = __builtin_amdgcn_mfma_f32_16x16x32_bf16(a, b1, acc1, 0, 0, 0);
    }
    // D layout: col = lane&15, row = (lane>>4)*4 + reg  [m89]
    #pragma unroll
    for (int j = 0; j < 4; j++) {
        int rr = grow0 + kb * 4 + j;
        if (rr < nrows) {
            float d = dinv[rr];
            OUT[(size_t)rr * 32 + m]      = f2bf(acc0[j] * d);
            OUT[(size_t)rr * 32 + 16 + m] = f2bf(acc1[j] * d);
        }
    }
}

// ------------------------------------------------------------------
// bf16 gather-aggregate core: 8 lanes/node, lane owns channels [c0..c0+3].
__device__ __forceinline__ float4 agg_gather_bf16(const unsigned short* __restrict__ HS,
                                                  const int* __restrict__ col,
                                                  int s0, int s1, int node, int c0) {
    float4 a0 = {0,0,0,0}, a1 = {0,0,0,0}, a2 = {0,0,0,0}, a3 = {0,0,0,0};
    int e = s0;
    for (; e + 3 < s1; e += 4) {
        int sA = col[e], sB = col[e + 1], sC = col[e + 2], sD = col[e + 3];
        ushort4 uA = *(const ushort4*)&HS[(size_t)sA * 32 + c0];
        ushort4 uB = *(const ushort4*)&HS[(size_t)sB * 32 + c0];
        ushort4 uC = *(const ushort4*)&HS[(size_t)sC * 32 + c0];
        ushort4 uD = *(const ushort4*)&HS[(size_t)sD * 32 + c0];
        a0.x += bf2f(uA.x); a0.y += bf2f(uA.y); a0.z += bf2f(uA.z); a0.w += bf2f(uA.w);
        a1.x += bf2f(uB.x); a1.y += bf2f(uB.y); a1.z += bf2f(uB.z); a1.w += bf2f(uB.w);
        a2.x += bf2f(uC.x); a2.y += bf2f(uC.y); a2.z += bf2f(uC.z); a2.w += bf2f(uC.w);
        a3.x += bf2f(uD.x); a3.y += bf2f(uD.y); a3.z += bf2f(uD.z); a3.w += bf2f(uD.w);
    }
    for (; e < s1; e++) {
        int sA = col[e];
        ushort4 uA = *(const ushort4*)&HS[(size_t)sA * 32 + c0];
        a0.x += bf2f(uA.x); a0.y += bf2f(uA.y); a0.z += bf2f(uA.z); a0.w += bf2f(uA.w);
    }
    ushort4 uS = *(const ushort4*)&HS[(size_t)node * 32 + c0];
    float4 acc;
    acc.x = a0.x + a1.x + a2.x + a3.x + bf2f(uS.x);
    acc.y = a0.y + a1.y + a2.y + a3.y + bf2f(uS.y);
    acc.z = a0.z + a1.z + a2.z + a3.z + bf2f(uS.z);
    acc.w = a0.w + a1.w + a2.w + a3.w + bf2f(uS.w);
    return acc;
}

// fuse: a = relu(dinv*(agg hs1) + b1); OUT(bf16) = dinv * (a @ W2)  [32 -> 32]
__global__ __launch_bounds__(256) void k_fuse32(const unsigned short* __restrict__ HS,
                                                const int* __restrict__ row_ptr,
                                                const int* __restrict__ col,
                                                const float* __restrict__ dinv,
                                                const float* __restrict__ bin,
                                                const float* __restrict__ W,
                                                unsigned short* __restrict__ OUT, int n) {
    __shared__ float ws[32][32];
    {
        int i = threadIdx.x;                 // 256 float4s = 32x32
        int r = i / 8, c = (i % 8) * 4;
        *(float4*)&ws[r][c] = *(const float4*)&W[r * 32 + c];
    }
    __syncthreads();
    const int t    = threadIdx.x;
    const int node = blockIdx.x * 32 + t / 8;
    const int c0   = (t % 8) * 4;
    if (node >= n) return;
    const int s0 = row_ptr[node], s1 = row_ptr[node + 1];
    float4 acc = agg_gather_bf16(HS, col, s0, s1, node, c0);
    const float di = dinv[node];
    float4 b4 = *(const float4*)&bin[c0];
    float4 a;
    a.x = fmaxf(di * acc.x + b4.x, 0.f);
    a.y = fmaxf(di * acc.y + b4.y, 0.f);
    a.z = fmaxf(di * acc.z + b4.z, 0.f);
    a.w = fmaxf(di * acc.w + b4.w, 0.f);
    float4 o = {0,0,0,0};
    const int gb = (t & 63) & ~7;
    #pragma unroll
    for (int s = 0; s < 8; s++) {
        float4 as;
        as.x = __shfl(a.x, gb + s, 64);
        as.y = __shfl(a.y, gb + s, 64);
        as.z = __shfl(a.z, gb + s, 64);
        as.w = __shfl(a.w, gb + s, 64);
        const int k0 = s * 4;
        float4 w0 = *(const float4*)&ws[k0 + 0][c0];
        float4 w1 = *(const float4*)&ws[k0 + 1][c0];
        float4 w2 = *(const float4*)&ws[k0 + 2][c0];
        float4 w3 = *(const float4*)&ws[k0 + 3][c0];
        o.x += as.x*w0.x + as.y*w1.x + as.z*w2.x + as.w*w3.x;
        o.y += as.x*w0.y + as.y*w1.y + as.z*w2.y + as.w*w3.y;
        o.z += as.x*w0.z + as.y*w1.z + as.z*w2.z + as.w*w3.z;
        o.w += as.x*w0.w + as.y*w1.w + as.z*w2.w + as.w*w3.w;
    }
    ushort4 st;
    st.x = f2bf(o.x * di); st.y = f2bf(o.y * di);
    st.z = f2bf(o.z * di); st.w = f2bf(o.w * di);
    *(ushort4*)&OUT[(size_t)node * 32 + c0] = st;
}

// agg + bias + relu + dinv scale: OUT(bf16) = dinv.*relu(dinv*agg(HS)+b)
__global__ __launch_bounds__(256) void k_aggscale(const unsigned short* __restrict__ HS,
                                                  const int* __restrict__ row_ptr,
                                                  const int* __restrict__ col,
                                                  const float* __restrict__ dinv,
                                                  const float* __restrict__ bin,
                                                  unsigned short* __restrict__ OUT, int n) {
    const int t    = threadIdx.x;
    const int node = blockIdx.x * 32 + t / 8;
    const int c0   = (t % 8) * 4;
    if (node >= n) return;
    const int s0 = row_ptr[node], s1 = row_ptr[node + 1];
    float4 acc = agg_gather_bf16(HS, col, s0, s1, node, c0);
    const float di = dinv[node];
    float4 b4 = *(const float4*)&bin[c0];
    ushort4 o;
    o.x = f2bf(di * fmaxf(di * acc.x + b4.x, 0.f));
    o.y = f2bf(di * fmaxf(di * acc.y + b4.y, 0.f));
    o.z = f2bf(di * fmaxf(di * acc.z + b4.z, 0.f));
    o.w = f2bf(di * fmaxf(di * acc.w + b4.w, 0.f));
    *(ushort4*)&OUT[(size_t)node * 32 + c0] = o;
}

// final: g = dinv*(agg ys2); h3 = g @ W3 + b3 [32->64]; out = log_softmax(h3)
__global__ __launch_bounds__(256) void k_fuseC(const unsigned short* __restrict__ YS,
                                               const int* __restrict__ row_ptr,
                                               const int* __restrict__ col,
                                               const float* __restrict__ dinv,
                                               const float* __restrict__ b3,
                                               const float* __restrict__ W,
                                               float* __restrict__ OUT, int n) {
    __shared__ float ws[32][64];
    {
        int i = threadIdx.x;                  // 512 float4s = 32x64 -> 2 each
        int r0w = i / 16, cw = (i % 16) * 4;
        *(float4*)&ws[r0w][cw]      = *(const float4*)&W[r0w * 64 + cw];
        *(float4*)&ws[r0w + 16][cw] = *(const float4*)&W[(r0w + 16) * 64 + cw];
    }
    __syncthreads();
    const int t    = threadIdx.x;
    const int node = blockIdx.x * 32 + t / 8;
    const int c0   = (t % 8) * 4;
    if (node >= n) return;
    const int s0 = row_ptr[node], s1 = row_ptr[node + 1];
    float4 acc = agg_gather_bf16(YS, col, s0, s1, node, c0);
    const float di = dinv[node];
    float4 g;
    g.x = di * acc.x; g.y = di * acc.y; g.z = di * acc.z; g.w = di * acc.w;
    float4 oL = {0,0,0,0}, oH = {0,0,0,0};
    const int gb = (t & 63) & ~7;
    #pragma unroll
    for (int s = 0; s < 8; s++) {
        float4 gs;
        gs.x = __shfl(g.x, gb + s, 64);
        gs.y = __shfl(g.y, gb + s, 64);
        gs.z = __shfl(g.z, gb + s, 64);
        gs.w = __shfl(g.w, gb + s, 64);
        const int k0 = s * 4;
        #pragma unroll
        for (int q = 0; q < 4; q++) {
            float gv = (q == 0) ? gs.x : (q == 1) ? gs.y : (q == 2) ? gs.z : gs.w;
            float4 wL = *(const float4*)&ws[k0 + q][c0];
            float4 wH = *(const float4*)&ws[k0 + q][32 + c0];
            oL.x += gv * wL.x; oL.y += gv * wL.y; oL.z += gv * wL.z; oL.w += gv * wL.w;
            oH.x += gv * wH.x; oH.y += gv * wH.y; oH.z += gv * wH.z; oH.w += gv * wH.w;
        }
    }
    float4 bL = *(const float4*)&b3[c0];
    float4 bH = *(const float4*)&b3[32 + c0];
    oL.x += bL.x; oL.y += bL.y; oL.z += bL.z; oL.w += bL.w;
    oH.x += bH.x; oH.y += bH.y; oH.z += bH.z; oH.w += bH.w;
    float m = fmaxf(fmaxf(fmaxf(oL.x, oL.y), fmaxf(oL.z, oL.w)),
                    fmaxf(fmaxf(oH.x, oH.y), fmaxf(oH.z, oH.w)));
    #pragma unroll
    for (int off = 1; off < 8; off <<= 1) m = fmaxf(m, __shfl_xor(m, off, 64));
    float sum = expf(oL.x - m) + expf(oL.y - m) + expf(oL.z - m) + expf(oL.w - m)
              + expf(oH.x - m) + expf(oH.y - m) + expf(oH.z - m) + expf(oH.w - m);
    #pragma unroll
    for (int off = 1; off < 8; off <<= 1) sum += __shfl_xor(sum, off, 64);
    float lse = m + logf(sum);
    float4 rL, rH;
    rL.x = oL.x - lse; rL.y = oL.y - lse; rL.z = oL.z - lse; rL.w = oL.w - lse;
    rH.x = oH.x - lse; rH.y = oH.y - lse; rH.z = oH.z - lse; rH.w = oH.w - lse;
    *(float4*)&OUT[(size_t)node * 64 + c0]      = rL;
    *(float4*)&OUT[(size_t)node * 64 + 32 + c0] = rH;
}

// ------------------------------------------------------------------
extern "C" void kernel_launch(void* const* d_in, const int* in_sizes, int n_in,
                              void* d_out, int out_size, void* d_ws, size_t ws_size,
                              hipStream_t stream) {
    const float* x  = (const float*)d_in[0];
    const int*   ei = (const int*)d_in[1];
    const float* W1 = (const float*)d_in[2];
    const float* b1 = (const float*)d_in[3];
    const float* W2 = (const float*)d_in[4];
    const float* b2 = (const float*)d_in[5];
    const float* W3 = (const float*)d_in[6];
    const float* b3 = (const float*)d_in[7];
    float* out = (float*)d_out;

    const int E = in_sizes[1] / 2;
    const int n = NN;
    const int* src = ei;
    const int* dst = ei + E;

    char* p = (char*)d_ws;
    auto alloc = [&](size_t bytes) -> void* {
        void* r = p;
        p += (bytes + 63) & ~(size_t)63;
        return r;
    };
    int*            bcnt    = (int*)alloc((size_t)NBUCK * 4);
    int*            bbase   = (int*)alloc((size_t)(NBUCK + 1) * 4);
    int*            bfill   = (int*)alloc((size_t)NBUCK * 4);
    unsigned*       part    = (unsigned*)alloc((size_t)E * 4);
    int*            row_ptr = (int*)alloc((size_t)(n + 1) * 4);
    int*            col     = (int*)alloc((size_t)E * 4);
    float*          dinv    = (float*)alloc((size_t)n * 4);
    unsigned short* wtbf    = (unsigned short*)alloc((size_t)512 * 32 * 2);
    unsigned short* hs1     = (unsigned short*)alloc((size_t)n * 32 * 2);  // reused as ys2
    unsigned short* hs2     = (unsigned short*)alloc((size_t)n * 32 * 2);

    const int NBLK_A = 256;
    const int chunk  = CDIV(E, NBLK_A);

    k_zero<<<1, 512, 0, stream>>>(bcnt, NBUCK);
    k_wconv<<<64, 256, 0, stream>>>(W1, wtbf);
    k_bcount<<<NBLK_A, 256, 0, stream>>>(dst, bcnt, E, chunk);
    k_bscan<<<1, 512, 0, stream>>>(bcnt, bbase, bfill, E);
    k_bpart<<<NBLK_A, 256, 0, stream>>>(src, dst, bfill, part, E, chunk);
    k_bbuild<<<NBUCK, 256, 0, stream>>>(part, bbase, row_ptr, dinv, col, n, E);

    // L1 GEMM (MFMA bf16): hs1 = bf16(dinv.*(x @ W1))
    k_gemm1<<<CDIV(n, 64), 256, 0, stream>>>(x, wtbf, dinv, hs1, n);
    // L1 agg + relu + L2 GEMM: hs2 = bf16(dinv.*(relu(dinv*agg(hs1)+b1) @ W2))
    k_fuse32<<<CDIV(n, 32), 256, 0, stream>>>(hs1, row_ptr, col, dinv, b1, W2, hs2, n);
    // L2 agg + relu + scale: ys2 = bf16(dinv.*relu(dinv*agg(hs2)+b2))  (reuse hs1)
    k_aggscale<<<CDIV(n, 32), 256, 0, stream>>>(hs2, row_ptr, col, dinv, b2, hs1, n);
    // L3 (commuted): out = lsm( (dinv*agg(ys2)) @ W3 + b3 )
    k_fuseC<<<CDIV(n, 32), 256, 0, stream>>>(hs1, row_ptr, col, dinv, b3, W3, out, n);
}